// Round 12
// baseline (240.572 us; speedup 1.0000x reference)
//
#include <hip/hip_runtime.h>
#include <stdint.h>

#define N_CELL 8192
#define N_DRUG 4096
#define E_CELL 262144
#define E_DRUG 131072
#define DOUT   128

typedef float f32x4 __attribute__((ext_vector_type(4)));
typedef short s16x8 __attribute__((ext_vector_type(8)));

// ---------------- workspace layout (float32 element offsets) ----------------
#define OFF_DEG_C   0u
#define OFF_DEG_D   8192u
#define OFF_CNT_C   12288u
#define OFF_CNT_D   20480u
#define OFF_CUR_C   24576u
#define OFF_CUR_D   32768u
#define OFF_START_C 36864u
#define OFF_START_D 45312u
#define OFF_EW_C    49664u
#define OFF_EW_D    311808u
#define OFF_SROW_C  442880u
#define OFF_SROW_D  705024u
#define OFF_SCOEF_C 836096u
#define OFF_SCOEF_D 1098240u
#define OFF_H_C     1229312u
#define OFF_H_D     2277888u
#define OFF_END     2802176u
// byte offsets past the f32 region
#define WT_C_BYTE   (OFF_END * 4u)                     // 11,208,704 ; 2MB
#define WT_D_BYTE   (WT_C_BYTE + 128u * 8192u * 2u)    // 13,305,856 ; 1MB
#define PART_C_BYTE 14354432u                          // 4 x 8192x128 f32 = 16MB
#define PART_D_BYTE 31131648u                          // 2 x 4096x128 f32 = 4MB
#define PART_END    35325952u

__device__ __forceinline__ unsigned short f2bf(float f) {
    union { float f; uint32_t u; } v; v.f = f;
    uint32_t u = v.u + 0x7fffu + ((v.u >> 16) & 1u);   // RNE
    return (unsigned short)(u >> 16);
}

// pack 8 f32 -> 8 bf16 (round-half-up) via v_perm
__device__ __forceinline__ s16x8 pack8(float4 x, float4 y) {
    union { float4 f; uint32_t u[4]; } a, b;
    a.f = x; b.f = y;
    union { uint32_t u[4]; s16x8 v; } r;
    r.u[0] = __builtin_amdgcn_perm(a.u[1] + 0x8000u, a.u[0] + 0x8000u, 0x07060302u);
    r.u[1] = __builtin_amdgcn_perm(a.u[3] + 0x8000u, a.u[2] + 0x8000u, 0x07060302u);
    r.u[2] = __builtin_amdgcn_perm(b.u[1] + 0x8000u, b.u[0] + 0x8000u, 0x07060302u);
    r.u[3] = __builtin_amdgcn_perm(b.u[3] + 0x8000u, b.u[2] + 0x8000u, 0x07060302u);
    return r.v;
}

// ---------------- K1: prep = init counters + zero h + build WT bf16 ----------------
__global__ __launch_bounds__(256) void k_prep(const float* __restrict__ Wc, const float* __restrict__ Wd,
                                              unsigned short* __restrict__ wtc, unsigned short* __restrict__ wtd,
                                              float* __restrict__ ws) {
    int bid = blockIdx.x, t = threadIdx.x;
    if (bid < 144) {
        int i = bid * 256 + t;
        ws[i] = (i < 12288) ? 1.0f : 0.0f;   // deg:=1 (self loop); cnt/cur := 0 bits
        return;
    }
    if (bid < 1680) {
        size_t i = (size_t)(bid - 144) * 256 + t;
        ((float4*)(ws + OFF_H_C))[i] = make_float4(0.f, 0.f, 0.f, 0.f);
        return;
    }
    int tile = bid - 1680;
    const float* W; unsigned short* wt; int K;
    if (tile < 1024) { W = Wc; wt = wtc; K = N_CELL; }
    else             { W = Wd; wt = wtd; K = N_DRUG; tile -= 1024; }
    int tk = tile >> 2, tc = tile & 3;
    __shared__ float tl[32][33];
    int c = t & 31, r8 = t >> 5;
#pragma unroll
    for (int p = 0; p < 4; ++p) {
        int row = r8 + p * 8;
        tl[row][c] = W[(size_t)(tk * 32 + row) * DOUT + tc * 32 + c];
    }
    __syncthreads();
#pragma unroll
    for (int p = 0; p < 4; ++p) {
        int c2 = r8 + p * 8;
        wt[(size_t)(tc * 32 + c2) * K + tk * 32 + c] = f2bf(tl[c][c2]);
    }
}

// ---------------- K2: ew gather + deg atomic + incoming-edge count ----------------
__global__ __launch_bounds__(256) void k_edge(const float* __restrict__ xc, const int* __restrict__ ec,
                                              const float* __restrict__ xd, const int* __restrict__ ed,
                                              float* __restrict__ ws) {
    int i = blockIdx.x * 256 + threadIdx.x;
    const float* x; const int* edges; float* ew; float* deg; int* cnt; int N, E, idx;
    if (i < E_CELL) {
        idx = i; x = xc; edges = ec; N = N_CELL; E = E_CELL;
        ew = ws + OFF_EW_C; deg = ws + OFF_DEG_C; cnt = (int*)(ws + OFF_CNT_C);
    } else {
        idx = i - E_CELL; if (idx >= E_DRUG) return;
        x = xd; edges = ed; N = N_DRUG; E = E_DRUG;
        ew = ws + OFF_EW_D; deg = ws + OFF_DEG_D; cnt = (int*)(ws + OFF_CNT_D);
    }
    int r = edges[idx], c = edges[E + idx];
    float w = x[(size_t)r * N + c];
    ew[idx] = w;
    unsafeAtomicAdd(&deg[c], w);
    atomicAdd(&cnt[c], 1);
}

// ---------------- K3: dinv (blocks 0..47) + exclusive scan (blocks 48,49) ----------------
__global__ __launch_bounds__(256) void k_scan2(float* ws) {
    int bid = blockIdx.x, t = threadIdx.x;
    if (bid < 48) {
        int i = bid * 256 + t;
        float d = ws[i];
        ws[i] = d > 0.f ? rsqrtf(fmaxf(d, 1e-30f)) : 0.f;
        return;
    }
    const int* cnt; int* start; int N, chunk;
    if (bid == 48) { cnt = (const int*)(ws + OFF_CNT_C); start = (int*)(ws + OFF_START_C); N = N_CELL; chunk = 32; }
    else           { cnt = (const int*)(ws + OFF_CNT_D); start = (int*)(ws + OFF_START_D); N = N_DRUG; chunk = 16; }
    __shared__ int sums[256];
    int base = t * chunk;
    int s = 0;
    for (int j = 0; j < chunk; ++j) s += cnt[base + j];
    sums[t] = s; __syncthreads();
    for (int off = 1; off < 256; off <<= 1) {
        int v = (t >= off) ? sums[t - off] : 0;
        __syncthreads();
        sums[t] += v;
        __syncthreads();
    }
    int run = sums[t] - s;
    for (int j = 0; j < chunk; ++j) { start[base + j] = run; run += cnt[base + j]; }
    if (t == 255) start[N] = run;
}

// ---------------- K4: fill CSR slots (srow, scoef) ----------------
__global__ __launch_bounds__(256) void k_fill(const int* __restrict__ ec, const int* __restrict__ ed,
                                              float* __restrict__ ws) {
    int i = blockIdx.x * 256 + threadIdx.x;
    const int* edges; const float* ew; const float* dinv; const int* start;
    int* cur; int* srow; float* scoef; int E, idx;
    if (i < E_CELL) {
        idx = i; edges = ec; E = E_CELL;
        ew = ws + OFF_EW_C; dinv = ws + OFF_DEG_C; start = (const int*)(ws + OFF_START_C);
        cur = (int*)(ws + OFF_CUR_C); srow = (int*)(ws + OFF_SROW_C); scoef = ws + OFF_SCOEF_C;
    } else {
        idx = i - E_CELL; if (idx >= E_DRUG) return;
        edges = ed; E = E_DRUG;
        ew = ws + OFF_EW_D; dinv = ws + OFF_DEG_D; start = (const int*)(ws + OFF_START_D);
        cur = (int*)(ws + OFF_CUR_D); srow = (int*)(ws + OFF_SROW_D); scoef = ws + OFF_SCOEF_D;
    }
    int r = edges[idx], c = edges[E + idx];
    float coef = dinv[r] * ew[idx] * dinv[c];
    int slot = start[c] + atomicAdd(&cur[c], 1);
    srow[slot] = r;
    scoef[slot] = coef;
}

// ---------------- K5: lean GEMM, K-split partials WITHOUT atomics ----------------
// r11's lean K-loop (32x128 tile, 4 waves, acc[2][2], 9.2KB LDS dbuf, B per-fragment
// from L2-resident WT). K-chunk = 2048 (32 steps) for BOTH graphs.
// EXPERIMENT: epilogue writes partials to disjoint scratch (plain stores) + k_reduce,
// eliminating the 10.5M memory-side atomic RMWs (the invariant across all ~150us rounds).
// Fallback (ws too small): f32 atomics, still 2x fewer than r11.
// cell: 256 mt x 4 ch = 1024 blocks; drug: 128 mt x 2 ch = 256. Grid 1280 = 5/CU.
__global__ __launch_bounds__(256, 6) void k_gemm(const float* __restrict__ xc, const float* __restrict__ xd,
                                                 const unsigned short* __restrict__ wtc,
                                                 const unsigned short* __restrict__ wtd,
                                                 float* __restrict__ ws,
                                                 float* __restrict__ partC, float* __restrict__ partD,
                                                 int usePart) {
    int bid = blockIdx.x, t = threadIdx.x;
    const float* x; const unsigned short* wt; float* hp; float* part; int K, mt, ch; size_t pstride;
    if (bid < 1024) {
        x = xc; wt = wtc; hp = ws + OFF_H_C; part = partC; K = N_CELL;
        mt = bid >> 2; ch = bid & 3; pstride = (size_t)N_CELL * DOUT;
    } else {
        int b = bid - 1024; x = xd; wt = wtd; hp = ws + OFF_H_D; part = partD; K = N_DRUG;
        mt = b >> 1; ch = b & 1; pstride = (size_t)N_DRUG * DOUT;
    }
    int k0 = ch * 2048;                                  // K-chunk base

    __shared__ alignas(16) unsigned short As[2][32][72];
    int lane = t & 63, wv = t >> 6;
    int l15 = lane & 15, l4 = lane >> 4;

    f32x4 acc[2][2] = {};

    int srow = t >> 3, sseg = t & 7;
    const float* abase = x + (size_t)(mt * 32 + srow) * K + k0 + sseg * 8;
    const unsigned short* bb = wt + (size_t)(wv * 32 + l15) * K + k0 + l4 * 8;
    const unsigned short* bb1 = bb + (size_t)16 * K;

    float4 X0, X1;

#define LOADA(KT) { const float4* _p = (const float4*)(abase + (size_t)(KT) * 64); \
                    X0 = _p[0]; X1 = _p[1]; }
#define WRITEA(BUF) { *(s16x8*)&As[BUF][srow][sseg * 8] = pack8(X0, X1); }

    LOADA(0);
    WRITEA(0);
    LOADA(1);
    __syncthreads();

#pragma unroll 1
    for (int kt = 0; kt < 32; ++kt) {
        // B loads first (FIFO: B-wait keeps A prefetch in flight)
        s16x8 bq00 = *(const s16x8*)(bb  + (size_t)kt * 64);
        s16x8 bq01 = *(const s16x8*)(bb  + (size_t)kt * 64 + 32);
        s16x8 bq10 = *(const s16x8*)(bb1 + (size_t)kt * 64);
        s16x8 bq11 = *(const s16x8*)(bb1 + (size_t)kt * 64 + 32);
        if (kt < 31) {
            WRITEA((kt + 1) & 1);
            if (kt < 30) LOADA(kt + 2);
        }
        int bf = kt & 1;
        {
            s16x8 a0 = *(const s16x8*)&As[bf][l15][l4 * 8];
            s16x8 a1 = *(const s16x8*)&As[bf][16 + l15][l4 * 8];
            acc[0][0] = __builtin_amdgcn_mfma_f32_16x16x32_bf16(a0, bq00, acc[0][0], 0, 0, 0);
            acc[0][1] = __builtin_amdgcn_mfma_f32_16x16x32_bf16(a0, bq10, acc[0][1], 0, 0, 0);
            acc[1][0] = __builtin_amdgcn_mfma_f32_16x16x32_bf16(a1, bq00, acc[1][0], 0, 0, 0);
            acc[1][1] = __builtin_amdgcn_mfma_f32_16x16x32_bf16(a1, bq10, acc[1][1], 0, 0, 0);
        }
        {
            s16x8 a0 = *(const s16x8*)&As[bf][l15][32 + l4 * 8];
            s16x8 a1 = *(const s16x8*)&As[bf][16 + l15][32 + l4 * 8];
            acc[0][0] = __builtin_amdgcn_mfma_f32_16x16x32_bf16(a0, bq01, acc[0][0], 0, 0, 0);
            acc[0][1] = __builtin_amdgcn_mfma_f32_16x16x32_bf16(a0, bq11, acc[0][1], 0, 0, 0);
            acc[1][0] = __builtin_amdgcn_mfma_f32_16x16x32_bf16(a1, bq01, acc[1][0], 0, 0, 0);
            acc[1][1] = __builtin_amdgcn_mfma_f32_16x16x32_bf16(a1, bq11, acc[1][1], 0, 0, 0);
        }
        __syncthreads();
    }
#undef LOADA
#undef WRITEA
    // ---- epilogue: plain stores to partials (or atomic fallback) ----
    if (usePart) {
        float* dst = part + (size_t)ch * pstride;
#pragma unroll
        for (int m = 0; m < 2; ++m)
#pragma unroll
            for (int n = 0; n < 2; ++n) {
                int col = wv * 32 + n * 16 + l15;
                int row = mt * 32 + m * 16 + l4 * 4;
#pragma unroll
                for (int j = 0; j < 4; ++j)
                    dst[(size_t)(row + j) * DOUT + col] = acc[m][n][j];
            }
    } else {
#pragma unroll
        for (int m = 0; m < 2; ++m)
#pragma unroll
            for (int n = 0; n < 2; ++n) {
                int col = wv * 32 + n * 16 + l15;
                int row = mt * 32 + m * 16 + l4 * 4;
#pragma unroll
                for (int j = 0; j < 4; ++j)
                    unsafeAtomicAdd(&hp[(size_t)(row + j) * DOUT + col], acc[m][n][j]);
            }
    }
}

// ---------------- K5b: reduce partials -> h (coalesced) ----------------
__global__ __launch_bounds__(256) void k_reduce(const float* __restrict__ partC,
                                                const float* __restrict__ partD,
                                                float* __restrict__ ws) {
    int bid = blockIdx.x, t = threadIdx.x;
    if (bid < 1024) {
        size_t i = (size_t)bid * 256 + t;                // 262144 float4 = cell h
        const f32x4* p = (const f32x4*)partC;
        f32x4 s = p[i] + p[i + 262144] + p[i + 2 * 262144] + p[i + 3 * 262144];
        ((f32x4*)(ws + OFF_H_C))[i] = s;
    } else {
        size_t i = (size_t)(bid - 1024) * 256 + t;       // 131072 float4 = drug h
        const f32x4* p = (const f32x4*)partD;
        f32x4 s = p[i] + p[i + 131072];
        ((f32x4*)(ws + OFF_H_D))[i] = s;
    }
}

// ---------------- K6: CSR gather + self loop + bias + relu ----------------
__global__ __launch_bounds__(256) void k_gather(const float* __restrict__ ws,
                                                const float* __restrict__ bc, const float* __restrict__ bd,
                                                float* __restrict__ out) {
    int wv = threadIdx.x >> 6, lane = threadIdx.x & 63;
    int g = blockIdx.x * 4 + wv;
    const float* h; const int* srow; const float* scoef; const int* start; const float* dinv;
    const float* bvec; float* outp; int node;
    if (g < N_CELL) {
        node = g; h = ws + OFF_H_C; srow = (const int*)(ws + OFF_SROW_C); scoef = ws + OFF_SCOEF_C;
        start = (const int*)(ws + OFF_START_C); dinv = ws + OFF_DEG_C; bvec = bc; outp = out;
    } else {
        node = g - N_CELL; if (node >= N_DRUG) return;
        h = ws + OFF_H_D; srow = (const int*)(ws + OFF_SROW_D); scoef = ws + OFF_SCOEF_D;
        start = (const int*)(ws + OFF_START_D); dinv = ws + OFF_DEG_D; bvec = bd;
        outp = out + (size_t)N_CELL * DOUT;
    }
    float di = dinv[node], sc = di * di;
    float2 v = ((const float2*)(h + (size_t)node * DOUT))[lane];
    float ax = sc * v.x, ay = sc * v.y;
    int s0 = start[node], s1 = start[node + 1];
    int e = s0;
    for (; e + 3 < s1; e += 4) {
        int r0 = srow[e];     float c0 = scoef[e];
        int r1 = srow[e + 1]; float c1 = scoef[e + 1];
        int r2 = srow[e + 2]; float c2 = scoef[e + 2];
        int r3 = srow[e + 3]; float c3 = scoef[e + 3];
        float2 u0 = ((const float2*)(h + (size_t)r0 * DOUT))[lane];
        float2 u1 = ((const float2*)(h + (size_t)r1 * DOUT))[lane];
        float2 u2 = ((const float2*)(h + (size_t)r2 * DOUT))[lane];
        float2 u3 = ((const float2*)(h + (size_t)r3 * DOUT))[lane];
        ax += c0 * u0.x + c1 * u1.x + c2 * u2.x + c3 * u3.x;
        ay += c0 * u0.y + c1 * u1.y + c2 * u2.y + c3 * u3.y;
    }
    for (; e < s1; ++e) {
        int r = srow[e]; float cf = scoef[e];
        float2 u = ((const float2*)(h + (size_t)r * DOUT))[lane];
        ax += cf * u.x; ay += cf * u.y;
    }
    float2 bb = ((const float2*)bvec)[lane];
    ax = fmaxf(ax + bb.x, 0.f);
    ay = fmaxf(ay + bb.y, 0.f);
    float2 o; o.x = ax; o.y = ay;
    ((float2*)outp)[(size_t)node * 64 + lane] = o;
}

// ---------------- host ----------------
extern "C" void kernel_launch(void* const* d_in, const int* in_sizes, int n_in,
                              void* d_out, int out_size, void* d_ws, size_t ws_size,
                              hipStream_t stream) {
    const float* cell_feat = (const float*)d_in[0];
    const int*   cell_edge = (const int*)d_in[1];
    const float* W_cell    = (const float*)d_in[2];
    const float* b_cell    = (const float*)d_in[3];
    const float* drug_feat = (const float*)d_in[4];
    const int*   drug_edge = (const int*)d_in[5];
    const float* W_drug    = (const float*)d_in[6];
    const float* b_drug    = (const float*)d_in[7];
    float* out = (float*)d_out;
    float* ws  = (float*)d_ws;
    unsigned short* wtc = (unsigned short*)((char*)d_ws + WT_C_BYTE);
    unsigned short* wtd = (unsigned short*)((char*)d_ws + WT_D_BYTE);
    float* partC = (float*)((char*)d_ws + PART_C_BYTE);
    float* partD = (float*)((char*)d_ws + PART_D_BYTE);
    int usePart = (ws_size >= (size_t)PART_END) ? 1 : 0;   // ws_size fixed per harness -> deterministic

    k_prep<<<3216, 256, 0, stream>>>(W_cell, W_drug, wtc, wtd, ws);
    k_edge<<<(E_CELL + E_DRUG) / 256, 256, 0, stream>>>(cell_feat, cell_edge, drug_feat, drug_edge, ws);
    k_scan2<<<50, 256, 0, stream>>>(ws);
    k_fill<<<1536, 256, 0, stream>>>(cell_edge, drug_edge, ws);
    k_gemm<<<1280, 256, 0, stream>>>(cell_feat, drug_feat, wtc, wtd, ws, partC, partD, usePart);
    if (usePart) k_reduce<<<1536, 256, 0, stream>>>(partC, partD, ws);
    k_gather<<<3072, 256, 0, stream>>>(ws, b_cell, b_drug, out);
}

// Round 13
// 228.221 us; speedup vs baseline: 1.0541x; 1.0541x over previous
//
#include <hip/hip_runtime.h>
#include <stdint.h>

#define N_CELL 8192
#define N_DRUG 4096
#define E_CELL 262144
#define E_DRUG 131072
#define DOUT   128

typedef float f32x4 __attribute__((ext_vector_type(4)));
typedef short s16x8 __attribute__((ext_vector_type(8)));

// ---------------- workspace layout (float32 element offsets) ----------------
#define OFF_DEG_C   0u
#define OFF_DEG_D   8192u
#define OFF_CNT_C   12288u
#define OFF_CNT_D   20480u
#define OFF_CUR_C   24576u
#define OFF_CUR_D   32768u
#define OFF_START_C 36864u
#define OFF_START_D 45312u
#define OFF_EW_C    49664u
#define OFF_EW_D    311808u
#define OFF_SROW_C  442880u
#define OFF_SROW_D  705024u
#define OFF_SCOEF_C 836096u
#define OFF_SCOEF_D 1098240u
#define OFF_H_C     1229312u
#define OFF_H_D     2277888u
#define OFF_END     2802176u
// byte offsets past the f32 region
#define WT_C_BYTE   (OFF_END * 4u)
#define WT_D_BYTE   (WT_C_BYTE + 128u * 8192u * 2u)
#define PART_C_BYTE 14354432u
#define PART_D_BYTE 31131648u
#define PART_END    35325952u

__device__ __forceinline__ unsigned short f2bf(float f) {
    union { float f; uint32_t u; } v; v.f = f;
    uint32_t u = v.u + 0x7fffu + ((v.u >> 16) & 1u);   // RNE
    return (unsigned short)(u >> 16);
}

// pack 8 f32 -> 8 bf16 (round-half-up) via v_perm
__device__ __forceinline__ s16x8 pack8(float4 x, float4 y) {
    union { float4 f; uint32_t u[4]; } a, b;
    a.f = x; b.f = y;
    union { uint32_t u[4]; s16x8 v; } r;
    r.u[0] = __builtin_amdgcn_perm(a.u[1] + 0x8000u, a.u[0] + 0x8000u, 0x07060302u);
    r.u[1] = __builtin_amdgcn_perm(a.u[3] + 0x8000u, a.u[2] + 0x8000u, 0x07060302u);
    r.u[2] = __builtin_amdgcn_perm(b.u[1] + 0x8000u, b.u[0] + 0x8000u, 0x07060302u);
    r.u[3] = __builtin_amdgcn_perm(b.u[3] + 0x8000u, b.u[2] + 0x8000u, 0x07060302u);
    return r.v;
}

// ---------------- K1: prep = init counters + zero h + build WT bf16 ----------------
__global__ __launch_bounds__(256) void k_prep(const float* __restrict__ Wc, const float* __restrict__ Wd,
                                              unsigned short* __restrict__ wtc, unsigned short* __restrict__ wtd,
                                              float* __restrict__ ws) {
    int bid = blockIdx.x, t = threadIdx.x;
    if (bid < 144) {
        int i = bid * 256 + t;
        ws[i] = (i < 12288) ? 1.0f : 0.0f;   // deg:=1 (self loop); cnt/cur := 0 bits
        return;
    }
    if (bid < 1680) {
        size_t i = (size_t)(bid - 144) * 256 + t;
        ((float4*)(ws + OFF_H_C))[i] = make_float4(0.f, 0.f, 0.f, 0.f);
        return;
    }
    int tile = bid - 1680;
    const float* W; unsigned short* wt; int K;
    if (tile < 1024) { W = Wc; wt = wtc; K = N_CELL; }
    else             { W = Wd; wt = wtd; K = N_DRUG; tile -= 1024; }
    int tk = tile >> 2, tc = tile & 3;
    __shared__ float tl[32][33];
    int c = t & 31, r8 = t >> 5;
#pragma unroll
    for (int p = 0; p < 4; ++p) {
        int row = r8 + p * 8;
        tl[row][c] = W[(size_t)(tk * 32 + row) * DOUT + tc * 32 + c];
    }
    __syncthreads();
#pragma unroll
    for (int p = 0; p < 4; ++p) {
        int c2 = r8 + p * 8;
        wt[(size_t)(tc * 32 + c2) * K + tk * 32 + c] = f2bf(tl[c][c2]);
    }
}

// ---------------- K2: ew gather + deg atomic + incoming-edge count ----------------
__global__ __launch_bounds__(256) void k_edge(const float* __restrict__ xc, const int* __restrict__ ec,
                                              const float* __restrict__ xd, const int* __restrict__ ed,
                                              float* __restrict__ ws) {
    int i = blockIdx.x * 256 + threadIdx.x;
    const float* x; const int* edges; float* ew; float* deg; int* cnt; int N, E, idx;
    if (i < E_CELL) {
        idx = i; x = xc; edges = ec; N = N_CELL; E = E_CELL;
        ew = ws + OFF_EW_C; deg = ws + OFF_DEG_C; cnt = (int*)(ws + OFF_CNT_C);
    } else {
        idx = i - E_CELL; if (idx >= E_DRUG) return;
        x = xd; edges = ed; N = N_DRUG; E = E_DRUG;
        ew = ws + OFF_EW_D; deg = ws + OFF_DEG_D; cnt = (int*)(ws + OFF_CNT_D);
    }
    int r = edges[idx], c = edges[E + idx];
    float w = x[(size_t)r * N + c];
    ew[idx] = w;
    unsafeAtomicAdd(&deg[c], w);
    atomicAdd(&cnt[c], 1);
}

// ---------------- K3: dinv (blocks 0..47) + exclusive scan (blocks 48,49) ----------------
__global__ __launch_bounds__(256) void k_scan2(float* ws) {
    int bid = blockIdx.x, t = threadIdx.x;
    if (bid < 48) {
        int i = bid * 256 + t;
        float d = ws[i];
        ws[i] = d > 0.f ? rsqrtf(fmaxf(d, 1e-30f)) : 0.f;
        return;
    }
    const int* cnt; int* start; int N, chunk;
    if (bid == 48) { cnt = (const int*)(ws + OFF_CNT_C); start = (int*)(ws + OFF_START_C); N = N_CELL; chunk = 32; }
    else           { cnt = (const int*)(ws + OFF_CNT_D); start = (int*)(ws + OFF_START_D); N = N_DRUG; chunk = 16; }
    __shared__ int sums[256];
    int base = t * chunk;
    int s = 0;
    for (int j = 0; j < chunk; ++j) s += cnt[base + j];
    sums[t] = s; __syncthreads();
    for (int off = 1; off < 256; off <<= 1) {
        int v = (t >= off) ? sums[t - off] : 0;
        __syncthreads();
        sums[t] += v;
        __syncthreads();
    }
    int run = sums[t] - s;
    for (int j = 0; j < chunk; ++j) { start[base + j] = run; run += cnt[base + j]; }
    if (t == 255) start[N] = run;
}

// ---------------- K4: fill CSR slots (srow, scoef) ----------------
__global__ __launch_bounds__(256) void k_fill(const int* __restrict__ ec, const int* __restrict__ ed,
                                              float* __restrict__ ws) {
    int i = blockIdx.x * 256 + threadIdx.x;
    const int* edges; const float* ew; const float* dinv; const int* start;
    int* cur; int* srow; float* scoef; int E, idx;
    if (i < E_CELL) {
        idx = i; edges = ec; E = E_CELL;
        ew = ws + OFF_EW_C; dinv = ws + OFF_DEG_C; start = (const int*)(ws + OFF_START_C);
        cur = (int*)(ws + OFF_CUR_C); srow = (int*)(ws + OFF_SROW_C); scoef = ws + OFF_SCOEF_C;
    } else {
        idx = i - E_CELL; if (idx >= E_DRUG) return;
        edges = ed; E = E_DRUG;
        ew = ws + OFF_EW_D; dinv = ws + OFF_DEG_D; start = (const int*)(ws + OFF_START_D);
        cur = (int*)(ws + OFF_CUR_D); srow = (int*)(ws + OFF_SROW_D); scoef = ws + OFF_SCOEF_D;
    }
    int r = edges[idx], c = edges[E + idx];
    float coef = dinv[r] * ew[idx] * dinv[c];
    int slot = start[c] + atomicAdd(&cur[c], 1);
    srow[slot] = r;
    scoef[slot] = coef;
}

// ---------------- K5: GEMM with cross-barrier prefetch of BOTH operands ----------------
// Thundering-herd fix: every ~150us variant consumed loads issued at the top of the same
// barrier-delimited step -> all waves stall together (MfmaUtil 5% at 46% occupancy).
// Here: B fragments double-buffered in REGISTERS one iteration ahead (issued before the
// MFMA cluster, consumed after the next barrier); A is 2 iterations deep (reg + LDS dbuf).
// Block 32 rows x 128 cols, BK=128/iteration (16 its, K-chunk 2048), 16 MFMA/it/wave.
// LDS: As[2][32][136] ushort = 17KB (272B odd-x16 row stride -> ~2-way banks = free).
// Epilogue: plain stores to disjoint partials + k_reduce (no atomics).
// cell: 256 mt x 4 ch = 1024; drug: 128 mt x 2 ch = 256. Grid 1280.
__global__ __launch_bounds__(256, 3) void k_gemm(const float* __restrict__ xc, const float* __restrict__ xd,
                                                 const unsigned short* __restrict__ wtc,
                                                 const unsigned short* __restrict__ wtd,
                                                 float* __restrict__ ws,
                                                 float* __restrict__ partC, float* __restrict__ partD,
                                                 int usePart) {
    int bid = blockIdx.x, t = threadIdx.x;
    const float* x; const unsigned short* wt; float* hp; float* part; int K, mt, ch; size_t pstride;
    if (bid < 1024) {
        x = xc; wt = wtc; hp = ws + OFF_H_C; part = partC; K = N_CELL;
        mt = bid >> 2; ch = bid & 3; pstride = (size_t)N_CELL * DOUT;
    } else {
        int b = bid - 1024; x = xd; wt = wtd; hp = ws + OFF_H_D; part = partD; K = N_DRUG;
        mt = b >> 1; ch = b & 1; pstride = (size_t)N_DRUG * DOUT;
    }
    int k0 = ch * 2048;

    __shared__ alignas(16) unsigned short As[2][32][136];
    int lane = t & 63, wv = t >> 6;
    int l15 = lane & 15, l4 = lane >> 4;

    f32x4 acc00 = {}, acc01 = {}, acc10 = {}, acc11 = {};

    // A staging: thread -> row srow (0..31), seg sseg (0..7): 16 consecutive f32
    int srow = t >> 3, sseg = t & 7;
    const float* abase = x + (size_t)(mt * 32 + srow) * K + k0 + sseg * 16;
    // B: col group 0 at wv*32+l15, group 1 +16; per-iteration 4 k-slots of 32
    const unsigned short* bb  = wt + (size_t)(wv * 32 + l15) * K + k0 + l4 * 8;
    const unsigned short* bb1 = bb + (size_t)16 * K;

    float4 X0, X1, X2, X3;
    s16x8 BA0, BA1, BA2, BA3, BA4, BA5, BA6, BA7;
    s16x8 BB0, BB1, BB2, BB3, BB4, BB5, BB6, BB7;

#define LOADA(IT) { const float4* _p = (const float4*)(abase + (size_t)(IT) * 128); \
                    X0 = _p[0]; X1 = _p[1]; X2 = _p[2]; X3 = _p[3]; }
#define WRITEA(BUF) { *(s16x8*)&As[BUF][srow][sseg * 16]     = pack8(X0, X1); \
                      *(s16x8*)&As[BUF][srow][sseg * 16 + 8] = pack8(X2, X3); }
#define BLOADM(P0,P1,P2,P3,P4,P5,P6,P7, IT) { \
    P0 = *(const s16x8*)(bb  + (size_t)(IT) * 128); \
    P1 = *(const s16x8*)(bb  + (size_t)(IT) * 128 + 32); \
    P2 = *(const s16x8*)(bb  + (size_t)(IT) * 128 + 64); \
    P3 = *(const s16x8*)(bb  + (size_t)(IT) * 128 + 96); \
    P4 = *(const s16x8*)(bb1 + (size_t)(IT) * 128); \
    P5 = *(const s16x8*)(bb1 + (size_t)(IT) * 128 + 32); \
    P6 = *(const s16x8*)(bb1 + (size_t)(IT) * 128 + 64); \
    P7 = *(const s16x8*)(bb1 + (size_t)(IT) * 128 + 96); }
#define COMPUTEM(BUF, B0,B1,B2,B3,B4,B5,B6,B7) { \
    { s16x8 a0 = *(const s16x8*)&As[BUF][l15][l4 * 8]; \
      s16x8 a1 = *(const s16x8*)&As[BUF][16 + l15][l4 * 8]; \
      acc00 = __builtin_amdgcn_mfma_f32_16x16x32_bf16(a0, B0, acc00, 0, 0, 0); \
      acc01 = __builtin_amdgcn_mfma_f32_16x16x32_bf16(a0, B4, acc01, 0, 0, 0); \
      acc10 = __builtin_amdgcn_mfma_f32_16x16x32_bf16(a1, B0, acc10, 0, 0, 0); \
      acc11 = __builtin_amdgcn_mfma_f32_16x16x32_bf16(a1, B4, acc11, 0, 0, 0); } \
    { s16x8 a0 = *(const s16x8*)&As[BUF][l15][32 + l4 * 8]; \
      s16x8 a1 = *(const s16x8*)&As[BUF][16 + l15][32 + l4 * 8]; \
      acc00 = __builtin_amdgcn_mfma_f32_16x16x32_bf16(a0, B1, acc00, 0, 0, 0); \
      acc01 = __builtin_amdgcn_mfma_f32_16x16x32_bf16(a0, B5, acc01, 0, 0, 0); \
      acc10 = __builtin_amdgcn_mfma_f32_16x16x32_bf16(a1, B1, acc10, 0, 0, 0); \
      acc11 = __builtin_amdgcn_mfma_f32_16x16x32_bf16(a1, B5, acc11, 0, 0, 0); } \
    { s16x8 a0 = *(const s16x8*)&As[BUF][l15][64 + l4 * 8]; \
      s16x8 a1 = *(const s16x8*)&As[BUF][16 + l15][64 + l4 * 8]; \
      acc00 = __builtin_amdgcn_mfma_f32_16x16x32_bf16(a0, B2, acc00, 0, 0, 0); \
      acc01 = __builtin_amdgcn_mfma_f32_16x16x32_bf16(a0, B6, acc01, 0, 0, 0); \
      acc10 = __builtin_amdgcn_mfma_f32_16x16x32_bf16(a1, B2, acc10, 0, 0, 0); \
      acc11 = __builtin_amdgcn_mfma_f32_16x16x32_bf16(a1, B6, acc11, 0, 0, 0); } \
    { s16x8 a0 = *(const s16x8*)&As[BUF][l15][96 + l4 * 8]; \
      s16x8 a1 = *(const s16x8*)&As[BUF][16 + l15][96 + l4 * 8]; \
      acc00 = __builtin_amdgcn_mfma_f32_16x16x32_bf16(a0, B3, acc00, 0, 0, 0); \
      acc01 = __builtin_amdgcn_mfma_f32_16x16x32_bf16(a0, B7, acc01, 0, 0, 0); \
      acc10 = __builtin_amdgcn_mfma_f32_16x16x32_bf16(a1, B3, acc10, 0, 0, 0); \
      acc11 = __builtin_amdgcn_mfma_f32_16x16x32_bf16(a1, B7, acc11, 0, 0, 0); } }

    // prologue: LDS buf0 <- A(0); X <- A(1); BA <- B(0)
    LOADA(0);
    WRITEA(0);
    LOADA(1);
    BLOADM(BA0,BA1,BA2,BA3,BA4,BA5,BA6,BA7, 0);
    __syncthreads();

#pragma unroll 1
    for (int it2 = 0; it2 < 8; ++it2) {
        int itE = it2 * 2, itO = itE + 1;
        // ---- even iteration: consume BA / LDS buf (itE&1); prefetch BB(itO), A ----
        BLOADM(BB0,BB1,BB2,BB3,BB4,BB5,BB6,BB7, itO);
        WRITEA(itO & 1);                    // X holds A(itE+1)
        if (itE < 14) LOADA(itE + 2);
        COMPUTEM(itE & 1, BA0,BA1,BA2,BA3,BA4,BA5,BA6,BA7);
        __syncthreads();
        // ---- odd iteration: consume BB; prefetch BA(itO+1), A ----
        if (itO < 15) {
            BLOADM(BA0,BA1,BA2,BA3,BA4,BA5,BA6,BA7, itO + 1);
            WRITEA((itO + 1) & 1);          // X holds A(itO+1)
            if (itO < 14) LOADA(itO + 2);
        }
        COMPUTEM(itO & 1, BB0,BB1,BB2,BB3,BB4,BB5,BB6,BB7);
        __syncthreads();
    }
#undef LOADA
#undef WRITEA
#undef BLOADM
#undef COMPUTEM
    // ---- epilogue: plain stores to partials (or atomic fallback) ----
    if (usePart) {
        float* dst = part + (size_t)ch * pstride;
#pragma unroll
        for (int m = 0; m < 2; ++m)
#pragma unroll
            for (int n = 0; n < 2; ++n) {
                f32x4 a = (m == 0) ? (n == 0 ? acc00 : acc01) : (n == 0 ? acc10 : acc11);
                int col = wv * 32 + n * 16 + l15;
                int row = mt * 32 + m * 16 + l4 * 4;
#pragma unroll
                for (int j = 0; j < 4; ++j)
                    dst[(size_t)(row + j) * DOUT + col] = a[j];
            }
    } else {
#pragma unroll
        for (int m = 0; m < 2; ++m)
#pragma unroll
            for (int n = 0; n < 2; ++n) {
                f32x4 a = (m == 0) ? (n == 0 ? acc00 : acc01) : (n == 0 ? acc10 : acc11);
                int col = wv * 32 + n * 16 + l15;
                int row = mt * 32 + m * 16 + l4 * 4;
#pragma unroll
                for (int j = 0; j < 4; ++j)
                    unsafeAtomicAdd(&hp[(size_t)(row + j) * DOUT + col], a[j]);
            }
    }
}

// ---------------- K5b: reduce partials -> h (coalesced) ----------------
__global__ __launch_bounds__(256) void k_reduce(const float* __restrict__ partC,
                                                const float* __restrict__ partD,
                                                float* __restrict__ ws) {
    int bid = blockIdx.x, t = threadIdx.x;
    if (bid < 1024) {
        size_t i = (size_t)bid * 256 + t;                // 262144 float4 = cell h
        const f32x4* p = (const f32x4*)partC;
        f32x4 s = p[i] + p[i + 262144] + p[i + 2 * 262144] + p[i + 3 * 262144];
        ((f32x4*)(ws + OFF_H_C))[i] = s;
    } else {
        size_t i = (size_t)(bid - 1024) * 256 + t;       // 131072 float4 = drug h
        const f32x4* p = (const f32x4*)partD;
        f32x4 s = p[i] + p[i + 131072];
        ((f32x4*)(ws + OFF_H_D))[i] = s;
    }
}

// ---------------- K6: CSR gather + self loop + bias + relu ----------------
__global__ __launch_bounds__(256) void k_gather(const float* __restrict__ ws,
                                                const float* __restrict__ bc, const float* __restrict__ bd,
                                                float* __restrict__ out) {
    int wv = threadIdx.x >> 6, lane = threadIdx.x & 63;
    int g = blockIdx.x * 4 + wv;
    const float* h; const int* srow; const float* scoef; const int* start; const float* dinv;
    const float* bvec; float* outp; int node;
    if (g < N_CELL) {
        node = g; h = ws + OFF_H_C; srow = (const int*)(ws + OFF_SROW_C); scoef = ws + OFF_SCOEF_C;
        start = (const int*)(ws + OFF_START_C); dinv = ws + OFF_DEG_C; bvec = bc; outp = out;
    } else {
        node = g - N_CELL; if (node >= N_DRUG) return;
        h = ws + OFF_H_D; srow = (const int*)(ws + OFF_SROW_D); scoef = ws + OFF_SCOEF_D;
        start = (const int*)(ws + OFF_START_D); dinv = ws + OFF_DEG_D; bvec = bd;
        outp = out + (size_t)N_CELL * DOUT;
    }
    float di = dinv[node], sc = di * di;
    float2 v = ((const float2*)(h + (size_t)node * DOUT))[lane];
    float ax = sc * v.x, ay = sc * v.y;
    int s0 = start[node], s1 = start[node + 1];
    int e = s0;
    for (; e + 3 < s1; e += 4) {
        int r0 = srow[e];     float c0 = scoef[e];
        int r1 = srow[e + 1]; float c1 = scoef[e + 1];
        int r2 = srow[e + 2]; float c2 = scoef[e + 2];
        int r3 = srow[e + 3]; float c3 = scoef[e + 3];
        float2 u0 = ((const float2*)(h + (size_t)r0 * DOUT))[lane];
        float2 u1 = ((const float2*)(h + (size_t)r1 * DOUT))[lane];
        float2 u2 = ((const float2*)(h + (size_t)r2 * DOUT))[lane];
        float2 u3 = ((const float2*)(h + (size_t)r3 * DOUT))[lane];
        ax += c0 * u0.x + c1 * u1.x + c2 * u2.x + c3 * u3.x;
        ay += c0 * u0.y + c1 * u1.y + c2 * u2.y + c3 * u3.y;
    }
    for (; e < s1; ++e) {
        int r = srow[e]; float cf = scoef[e];
        float2 u = ((const float2*)(h + (size_t)r * DOUT))[lane];
        ax += cf * u.x; ay += cf * u.y;
    }
    float2 bb = ((const float2*)bvec)[lane];
    ax = fmaxf(ax + bb.x, 0.f);
    ay = fmaxf(ay + bb.y, 0.f);
    float2 o; o.x = ax; o.y = ay;
    ((float2*)outp)[(size_t)node * 64 + lane] = o;
}

// ---------------- host ----------------
extern "C" void kernel_launch(void* const* d_in, const int* in_sizes, int n_in,
                              void* d_out, int out_size, void* d_ws, size_t ws_size,
                              hipStream_t stream) {
    const float* cell_feat = (const float*)d_in[0];
    const int*   cell_edge = (const int*)d_in[1];
    const float* W_cell    = (const float*)d_in[2];
    const float* b_cell    = (const float*)d_in[3];
    const float* drug_feat = (const float*)d_in[4];
    const int*   drug_edge = (const int*)d_in[5];
    const float* W_drug    = (const float*)d_in[6];
    const float* b_drug    = (const float*)d_in[7];
    float* out = (float*)d_out;
    float* ws  = (float*)d_ws;
    unsigned short* wtc = (unsigned short*)((char*)d_ws + WT_C_BYTE);
    unsigned short* wtd = (unsigned short*)((char*)d_ws + WT_D_BYTE);
    float* partC = (float*)((char*)d_ws + PART_C_BYTE);
    float* partD = (float*)((char*)d_ws + PART_D_BYTE);
    int usePart = (ws_size >= (size_t)PART_END) ? 1 : 0;

    k_prep<<<3216, 256, 0, stream>>>(W_cell, W_drug, wtc, wtd, ws);
    k_edge<<<(E_CELL + E_DRUG) / 256, 256, 0, stream>>>(cell_feat, cell_edge, drug_feat, drug_edge, ws);
    k_scan2<<<50, 256, 0, stream>>>(ws);
    k_fill<<<1536, 256, 0, stream>>>(cell_edge, drug_edge, ws);
    k_gemm<<<1280, 256, 0, stream>>>(cell_feat, drug_feat, wtc, wtd, ws, partC, partD, usePart);
    if (usePart) k_reduce<<<1536, 256, 0, stream>>>(partC, partD, ws);
    k_gather<<<3072, 256, 0, stream>>>(ws, b_cell, b_drug, out);
}